// Round 4
// baseline (209.688 us; speedup 1.0000x reference)
//
#include <hip/hip_runtime.h>

typedef __attribute__((ext_vector_type(8))) short bf16x8;
typedef __attribute__((ext_vector_type(4))) float floatx4;

#define T_TREES 20
#define N_NODES 32      // padded (31 real internal nodes)
#define F_DIM 128
#define M_TILE 128      // 4 waves x 32 rows, wave-private leaf phase
#define S_SP 36         // sp stride (dwords): 32 rows + 4 pad (reads <=2-way conflict)

#define NLOG2E 1.4426950408889634f   // sigmoid scale, applied in EPILOGUE (fma), not to weights

__device__ __forceinline__ short f2bf(float f) {
    unsigned u = __float_as_uint(f);
    u += 0x7fffu + ((u >> 16) & 1u);   // RNE — matches numpy/ml_dtypes bf16 cast
    return (short)(u >> 16);
}
__device__ __forceinline__ float bf2f(short h) {
    return __uint_as_float(((unsigned)(unsigned short)h) << 16);
}

// sigma(z) with u = -z*log2(e) already: 1/(1+2^u). 2 VALU + 2 trans ops.
__device__ __forceinline__ float sig_from_scaled(float u) {
    return __builtin_amdgcn_rcpf(1.f + __builtin_amdgcn_exp2f(u));
}

// ---------------- prep: RAW bf16 masked weights (unscaled -> exact bf16 grid).
// Bias pre-scaled by -log2e; leaf values from bf16(ll). UNCHANGED numerics (verified r2).
__global__ void nrf_prep(const float* __restrict__ sw, const float* __restrict__ sb,
                         const float* __restrict__ ll, const float* __restrict__ tw,
                         const float* __restrict__ fm,
                         short* __restrict__ w_all, float* __restrict__ bias_p,
                         float* __restrict__ lv0) {
    int t = blockIdx.x, tid = threadIdx.x;
    float m = -1e30f;
    for (int i = 0; i < T_TREES; ++i) m = fmaxf(m, bf2f(f2bf(tw[i])));
    float s = 0.f;
    for (int i = 0; i < T_TREES; ++i) s += __expf(bf2f(f2bf(tw[i])) - m);
    float wt = __expf(bf2f(f2bf(tw[t])) - m) / s;

    const float* fmt = fm + t * F_DIM;
    const float* swt = sw + t * 31 * F_DIM;
    for (int idx = tid; idx < N_NODES * F_DIM; idx += blockDim.x) {
        int n = idx >> 7, f = idx & 127;
        short wb = (n < 31 && fmt[f] != 0.f) ? f2bf(swt[n * F_DIM + f]) : (short)0;
        w_all[t * (N_NODES * F_DIM) + idx] = wb;
    }
    if (tid < N_NODES) {
        float bv = (tid < 31) ? bf2f(f2bf(sb[t * 31 + tid])) : 0.f;
        bias_p[t * N_NODES + tid] = bv * (-NLOG2E);
        float a  = bf2f(f2bf(ll[(t * 32 + tid) * 2 + 0]));
        float bb = bf2f(f2bf(ll[(t * 32 + tid) * 2 + 1]));
        float mx = fmaxf(a, bb);
        float e0 = __expf(a - mx), e1 = __expf(bb - mx);
        lv0[t * N_NODES + tid] = wt * e0 / (e0 + e1);
    }
}

// ---------------- main: single-pass 20 trees; tree loop capped at unroll 2 so the
// hot body stays I$-resident (~2-4 KB) instead of a ~40 KB fully-unrolled stream.
__global__ __launch_bounds__(256) void nrf_main(const float* __restrict__ x,
        const short* __restrict__ w_all, const float* __restrict__ bias_p,
        const float* __restrict__ lv0, float* __restrict__ out) {
    __shared__ float sp_all[4][N_NODES * S_SP];   // one patch per wave
    __shared__ float lv_s[T_TREES * N_NODES];
    __shared__ float bias_s[T_TREES * N_NODES];

    int tid = threadIdx.x;
    int wave = tid >> 6, lane = tid & 63;
    int q = lane >> 4, c16 = lane & 15;

    for (int i = tid; i < T_TREES * N_NODES; i += 256) { lv_s[i] = lv0[i]; bias_s[i] = bias_p[i]; }

    float* spb = sp_all[wave];
    int rowBase = blockIdx.x * M_TILE + wave * 32;   // this wave's 32 rows

    // A fragments: bf16(x), reused by all 20 trees -> registers. A-layout m=lane&15, k=q*8+j.
    bf16x8 afrag[2][4];
    #pragma unroll
    for (int mi = 0; mi < 2; ++mi) {
        const float* xr = x + (size_t)(rowBase + mi * 16 + c16) * F_DIM;
        #pragma unroll
        for (int ks = 0; ks < 4; ++ks) {
            const float4* p = (const float4*)(xr + ks * 32 + q * 8);
            float4 f0 = p[0], f1 = p[1];
            bf16x8 v;
            v[0]=f2bf(f0.x); v[1]=f2bf(f0.y); v[2]=f2bf(f0.z); v[3]=f2bf(f0.w);
            v[4]=f2bf(f1.x); v[5]=f2bf(f1.y); v[6]=f2bf(f1.z); v[7]=f2bf(f1.w);
            afrag[mi][ks] = v;
        }
    }

    int s = lane & 15, h = lane >> 4;   // leaf job: rows s & s+16, quarter-subtree h
    int s_node = 3 + h;                 // quarter root (level-2 node)
    float acc0 = 0.f, acc1 = 0.f;
    __syncthreads();                    // ONLY barrier: lv_s/bias_s ready

    #pragma unroll 2
    for (int t = 0; t < T_TREES; ++t) {
        // B fragments from global (L2-resident), issued FIRST in the body so the
        // 2-wide unroll window can hoist them over the previous tree's leaf phase.
        bf16x8 bfrag[2][4];
        const short* wt = w_all + t * (N_NODES * F_DIM);
        #pragma unroll
        for (int ni = 0; ni < 2; ++ni) {
            const short* wr = wt + (ni * 16 + c16) * F_DIM;
            #pragma unroll
            for (int ks = 0; ks < 4; ++ks)
                bfrag[ni][ks] = *(const bf16x8*)(wr + ks * 32 + q * 8);
        }
        floatx4 acc[2][2];
        #pragma unroll
        for (int mi = 0; mi < 2; ++mi)
            #pragma unroll
            for (int ni = 0; ni < 2; ++ni)
                acc[mi][ni] = (floatx4){0.f,0.f,0.f,0.f};
        #pragma unroll
        for (int ks = 0; ks < 4; ++ks)
            #pragma unroll
            for (int mi = 0; mi < 2; ++mi)
                #pragma unroll
                for (int ni = 0; ni < 2; ++ni)
                    acc[mi][ni] = __builtin_amdgcn_mfma_f32_16x16x32_bf16(
                        afrag[mi][ks], bfrag[ni][ks], acc[mi][ni], 0, 0, 0);

        // epilogue: u = fma(acc, -log2e, bias*(-log2e)); sigma = rcp(1+exp2(u));
        // transposed wave-private store
        #pragma unroll
        for (int ni = 0; ni < 2; ++ni) {
            int col = ni * 16 + c16;
            float bv = bias_s[t * N_NODES + col];
            #pragma unroll
            for (int mi = 0; mi < 2; ++mi) {
                float4 v;
                v.x = sig_from_scaled(fmaf(acc[mi][ni][0], -NLOG2E, bv));
                v.y = sig_from_scaled(fmaf(acc[mi][ni][1], -NLOG2E, bv));
                v.z = sig_from_scaled(fmaf(acc[mi][ni][2], -NLOG2E, bv));
                v.w = sig_from_scaled(fmaf(acc[mi][ni][3], -NLOG2E, bv));
                *(float4*)&spb[col * S_SP + mi * 16 + q * 4] = v;
            }
        }
        // leaf phase: wave-private LDS, DS ops in-order per wave -> NO barrier.
        float g0a = spb[s],                          g0b = spb[s + 16];
        int n1 = 1 + (h >> 1);
        float g1a = spb[n1 * S_SP + s],              g1b = spb[n1 * S_SP + s + 16];
        float g2a = spb[s_node * S_SP + s],          g2b = spb[s_node * S_SP + s + 16];
        int n3a = 2 * s_node + 1, n3b = 2 * s_node + 2;
        float g3aa = spb[n3a * S_SP + s],            g3ab = spb[n3a * S_SP + s + 16];
        float g3ba = spb[n3b * S_SP + s],            g3bb = spb[n3b * S_SP + s + 16];
        int n4 = 4 * s_node + 3;
        float g4aa = spb[n4 * S_SP + s],             g4ab = spb[n4 * S_SP + s + 16];
        float g4ba = spb[(n4+1) * S_SP + s],         g4bb = spb[(n4+1) * S_SP + s + 16];
        float g4ca = spb[(n4+2) * S_SP + s],         g4cb = spb[(n4+2) * S_SP + s + 16];
        float g4da = spb[(n4+3) * S_SP + s],         g4db = spb[(n4+3) * S_SP + s + 16];

        const float* lvt = &lv_s[t * N_NODES + h * 8];  // shared by both rows

        {   // row s
            float f0 = (h & 2) ? g0a : 1.f - g0a;
            float f1 = (h & 1) ? g1a : 1.f - g1a;
            float pre = f0 * f1;
            float p1 = pre * g2a, p0 = pre - p1;
            float q1 = p0 * g3aa, q0 = p0 - q1;
            float q3 = p1 * g3ba, q2 = p1 - q3;
            float r1 = q0 * g4aa, r0 = q0 - r1;
            float r3 = q1 * g4ba, r2 = q1 - r3;
            float r5 = q2 * g4ca, r4 = q2 - r5;
            float r7 = q3 * g4da, r6 = q3 - r7;
            acc0 += r0*lvt[0] + r1*lvt[1] + r2*lvt[2] + r3*lvt[3]
                  + r4*lvt[4] + r5*lvt[5] + r6*lvt[6] + r7*lvt[7];
        }
        {   // row s+16
            float f0 = (h & 2) ? g0b : 1.f - g0b;
            float f1 = (h & 1) ? g1b : 1.f - g1b;
            float pre = f0 * f1;
            float p1 = pre * g2b, p0 = pre - p1;
            float q1 = p0 * g3ab, q0 = p0 - q1;
            float q3 = p1 * g3bb, q2 = p1 - q3;
            float r1 = q0 * g4ab, r0 = q0 - r1;
            float r3 = q1 * g4bb, r2 = q1 - r3;
            float r5 = q2 * g4cb, r4 = q2 - r5;
            float r7 = q3 * g4db, r6 = q3 - r7;
            acc1 += r0*lvt[0] + r1*lvt[1] + r2*lvt[2] + r3*lvt[3]
                  + r4*lvt[4] + r5*lvt[5] + r6*lvt[6] + r7*lvt[7];
        }
    }

    // cross-quarter reduce inside the wave; out1 = 1 - out0 (prob mass sums to 1)
    acc0 += __shfl_xor(acc0, 16, 64);
    acc0 += __shfl_xor(acc0, 32, 64);
    acc1 += __shfl_xor(acc1, 16, 64);
    acc1 += __shfl_xor(acc1, 32, 64);
    if (h == 0) {
        float2 o0; o0.x = acc0; o0.y = 1.f - acc0;
        *(float2*)(out + (size_t)(rowBase + s) * 2) = o0;
        float2 o1; o1.x = acc1; o1.y = 1.f - acc1;
        *(float2*)(out + (size_t)(rowBase + 16 + s) * 2) = o1;
    }
}

extern "C" void kernel_launch(void* const* d_in, const int* in_sizes, int n_in,
                              void* d_out, int out_size, void* d_ws, size_t ws_size,
                              hipStream_t stream) {
    const float* x  = (const float*)d_in[0];
    const float* sw = (const float*)d_in[1];
    const float* sb = (const float*)d_in[2];
    const float* ll = (const float*)d_in[3];
    const float* tw = (const float*)d_in[4];
    const float* fm = (const float*)d_in[5];
    float* out = (float*)d_out;

    short* w_all  = (short*)d_ws;                         // 20*32*128*2 = 163840 B
    float* bias_p = (float*)((char*)d_ws + 163840);       // 2560 B
    float* lv0    = (float*)((char*)d_ws + 166400);       // 2560 B

    nrf_prep<<<T_TREES, 256, 0, stream>>>(sw, sb, ll, tw, fm, w_all, bias_p, lv0);

    int B = in_sizes[0] / F_DIM;                          // 131072
    nrf_main<<<B / M_TILE, 256, 0, stream>>>(x, w_all, bias_p, lv0, out);
}

// Round 5
// 188.715 us; speedup vs baseline: 1.1111x; 1.1111x over previous
//
#include <hip/hip_runtime.h>

typedef __attribute__((ext_vector_type(8))) short bf16x8;
typedef __attribute__((ext_vector_type(4))) float floatx4;

#define T_TREES 20
#define N_NODES 32      // padded (31 real internal nodes)
#define F_DIM 128
#define M_TILE 128      // 4 waves x 32 rows, wave-private leaf phase
#define S_SP 36         // sp stride (dwords): 32 rows + 4 pad (reads <=2-way conflict)

#define NLOG2E 1.4426950408889634f   // sigmoid scale, applied in EPILOGUE (fma), not to weights

__device__ __forceinline__ short f2bf(float f) {
    unsigned u = __float_as_uint(f);
    u += 0x7fffu + ((u >> 16) & 1u);   // RNE — matches numpy/ml_dtypes bf16 cast
    return (short)(u >> 16);
}
__device__ __forceinline__ float bf2f(short h) {
    return __uint_as_float(((unsigned)(unsigned short)h) << 16);
}

// sigma(z) with u = -z*log2(e) already: 1/(1+2^u). 2 VALU + 2 trans ops.
__device__ __forceinline__ float sig_from_scaled(float u) {
    return __builtin_amdgcn_rcpf(1.f + __builtin_amdgcn_exp2f(u));
}

// ---------------- prep: RAW bf16 masked weights (unscaled -> exact bf16 grid).
// Parallelized: grid (20 trees, 8 node-slices) = 160 blocks, 2 coalesced iters each.
// tw staged via LDS (kills the 40-deep serial HBM-load chain); softmax order identical.
__global__ void nrf_prep(const float* __restrict__ sw, const float* __restrict__ sb,
                         const float* __restrict__ ll, const float* __restrict__ tw,
                         const float* __restrict__ fm,
                         short* __restrict__ w_all, float* __restrict__ bias_p,
                         float* __restrict__ lv0) {
    int t = blockIdx.x, slice = blockIdx.y, tid = threadIdx.x;

    const float* fmt = fm + t * F_DIM;
    const float* swt = sw + t * 31 * F_DIM;
    int idx = slice * 512 + tid;          // 4 nodes x 128 feats per slice
    #pragma unroll
    for (int r = 0; r < 2; ++r, idx += 256) {
        int n = idx >> 7, f = idx & 127;
        // mask is 0/1: bf16(sw*fm) == bf16(sw)*fm exactly. Store UNSCALED bf16.
        short wb = (n < 31 && fmt[f] != 0.f) ? f2bf(swt[n * F_DIM + f]) : (short)0;
        w_all[t * (N_NODES * F_DIM) + idx] = wb;
    }

    if (slice == 0) {
        __shared__ float tws[T_TREES];
        if (tid < T_TREES) tws[tid] = tw[tid];
        __syncthreads();
        if (tid < N_NODES) {
            // same reduction ORDER as the verified kernel -> bit-identical wt
            float m = -1e30f;
            for (int i = 0; i < T_TREES; ++i) m = fmaxf(m, bf2f(f2bf(tws[i])));
            float s = 0.f;
            for (int i = 0; i < T_TREES; ++i) s += __expf(bf2f(f2bf(tws[i])) - m);
            float wt = __expf(bf2f(f2bf(tws[t])) - m) / s;

            float bv = (tid < 31) ? bf2f(f2bf(sb[t * 31 + tid])) : 0.f;
            bias_p[t * N_NODES + tid] = bv * (-NLOG2E);
            float a  = bf2f(f2bf(ll[(t * 32 + tid) * 2 + 0]));
            float bb = bf2f(f2bf(ll[(t * 32 + tid) * 2 + 1]));
            float mx = fmaxf(a, bb);
            float e0 = __expf(a - mx), e1 = __expf(bb - mx);
            lv0[t * N_NODES + tid] = wt * e0 / (e0 + e1);
        }
    }
}

// ---------------- main: r2-verified body (full unroll), zero barriers in tree loop.
// NEW: co-resident blocks rotate tree order (offsets 0/5/10/15) to de-phase pipe usage.
__global__ __launch_bounds__(256) void nrf_main(const float* __restrict__ x,
        const short* __restrict__ w_all, const float* __restrict__ bias_p,
        const float* __restrict__ lv0, float* __restrict__ out) {
    __shared__ float sp_all[4][N_NODES * S_SP];   // one patch per wave
    __shared__ float lv_s[T_TREES * N_NODES];
    __shared__ float bias_s[T_TREES * N_NODES];

    int tid = threadIdx.x;
    int wave = tid >> 6, lane = tid & 63;
    int q = lane >> 4, c16 = lane & 15;

    // blocks c, c+256, c+512, c+768 co-reside on a CU -> give them offsets 0,5,10,15
    int trot = (blockIdx.x >> 8) * 5;

    // stage lv/bias PRE-ROTATED so the loop uses compile-time LDS indices
    for (int i = tid; i < T_TREES * N_NODES; i += 256) {
        int tree = i >> 5;
        int tsrc = tree + trot; if (tsrc >= T_TREES) tsrc -= T_TREES;
        int src = tsrc * N_NODES + (i & 31);
        lv_s[i] = lv0[src];
        bias_s[i] = bias_p[src];
    }

    float* spb = sp_all[wave];
    int rowBase = blockIdx.x * M_TILE + wave * 32;   // this wave's 32 rows

    // A fragments: bf16(x), reused by all 20 trees -> registers. A-layout m=lane&15, k=q*8+j.
    bf16x8 afrag[2][4];
    #pragma unroll
    for (int mi = 0; mi < 2; ++mi) {
        const float* xr = x + (size_t)(rowBase + mi * 16 + c16) * F_DIM;
        #pragma unroll
        for (int ks = 0; ks < 4; ++ks) {
            const float4* p = (const float4*)(xr + ks * 32 + q * 8);
            float4 f0 = p[0], f1 = p[1];
            bf16x8 v;
            v[0]=f2bf(f0.x); v[1]=f2bf(f0.y); v[2]=f2bf(f0.z); v[3]=f2bf(f0.w);
            v[4]=f2bf(f1.x); v[5]=f2bf(f1.y); v[6]=f2bf(f1.z); v[7]=f2bf(f1.w);
            afrag[mi][ks] = v;
        }
    }

    int s = lane & 15, h = lane >> 4;   // leaf job: rows s & s+16, quarter-subtree h
    int s_node = 3 + h;                 // quarter root (level-2 node)
    float acc0 = 0.f, acc1 = 0.f;
    __syncthreads();                    // ONLY barrier: lv_s/bias_s ready

    #pragma unroll
    for (int tt = 0; tt < T_TREES; ++tt) {
        int t = tt + trot; if (t >= T_TREES) t -= T_TREES;   // rotated global tree index
        // B fragments from global (L2-resident). No barrier ahead -> compiler can
        // hoist these over the previous tree's leaf phase (software pipelining).
        bf16x8 bfrag[2][4];
        const short* wtp = w_all + t * (N_NODES * F_DIM);
        #pragma unroll
        for (int ni = 0; ni < 2; ++ni) {
            const short* wr = wtp + (ni * 16 + c16) * F_DIM;
            #pragma unroll
            for (int ks = 0; ks < 4; ++ks)
                bfrag[ni][ks] = *(const bf16x8*)(wr + ks * 32 + q * 8);
        }
        floatx4 acc[2][2];
        #pragma unroll
        for (int mi = 0; mi < 2; ++mi)
            #pragma unroll
            for (int ni = 0; ni < 2; ++ni)
                acc[mi][ni] = (floatx4){0.f,0.f,0.f,0.f};
        #pragma unroll
        for (int ks = 0; ks < 4; ++ks)
            #pragma unroll
            for (int mi = 0; mi < 2; ++mi)
                #pragma unroll
                for (int ni = 0; ni < 2; ++ni)
                    acc[mi][ni] = __builtin_amdgcn_mfma_f32_16x16x32_bf16(
                        afrag[mi][ks], bfrag[ni][ks], acc[mi][ni], 0, 0, 0);

        // epilogue: u = fma(acc, -log2e, bias*(-log2e)); sigma = rcp(1+exp2(u));
        // transposed wave-private store
        #pragma unroll
        for (int ni = 0; ni < 2; ++ni) {
            int col = ni * 16 + c16;
            float bv = bias_s[tt * N_NODES + col];
            #pragma unroll
            for (int mi = 0; mi < 2; ++mi) {
                float4 v;
                v.x = sig_from_scaled(fmaf(acc[mi][ni][0], -NLOG2E, bv));
                v.y = sig_from_scaled(fmaf(acc[mi][ni][1], -NLOG2E, bv));
                v.z = sig_from_scaled(fmaf(acc[mi][ni][2], -NLOG2E, bv));
                v.w = sig_from_scaled(fmaf(acc[mi][ni][3], -NLOG2E, bv));
                *(float4*)&spb[col * S_SP + mi * 16 + q * 4] = v;
            }
        }
        // leaf phase: wave-private LDS, DS ops in-order per wave -> NO barrier.
        float g0a = spb[s],                          g0b = spb[s + 16];
        int n1 = 1 + (h >> 1);
        float g1a = spb[n1 * S_SP + s],              g1b = spb[n1 * S_SP + s + 16];
        float g2a = spb[s_node * S_SP + s],          g2b = spb[s_node * S_SP + s + 16];
        int n3a = 2 * s_node + 1, n3b = 2 * s_node + 2;
        float g3aa = spb[n3a * S_SP + s],            g3ab = spb[n3a * S_SP + s + 16];
        float g3ba = spb[n3b * S_SP + s],            g3bb = spb[n3b * S_SP + s + 16];
        int n4 = 4 * s_node + 3;
        float g4aa = spb[n4 * S_SP + s],             g4ab = spb[n4 * S_SP + s + 16];
        float g4ba = spb[(n4+1) * S_SP + s],         g4bb = spb[(n4+1) * S_SP + s + 16];
        float g4ca = spb[(n4+2) * S_SP + s],         g4cb = spb[(n4+2) * S_SP + s + 16];
        float g4da = spb[(n4+3) * S_SP + s],         g4db = spb[(n4+3) * S_SP + s + 16];

        const float* lvt = &lv_s[tt * N_NODES + h * 8];  // shared by both rows

        {   // row s
            float f0 = (h & 2) ? g0a : 1.f - g0a;
            float f1 = (h & 1) ? g1a : 1.f - g1a;
            float pre = f0 * f1;
            float p1 = pre * g2a, p0 = pre - p1;
            float q1 = p0 * g3aa, q0 = p0 - q1;
            float q3 = p1 * g3ba, q2 = p1 - q3;
            float r1 = q0 * g4aa, r0 = q0 - r1;
            float r3 = q1 * g4ba, r2 = q1 - r3;
            float r5 = q2 * g4ca, r4 = q2 - r5;
            float r7 = q3 * g4da, r6 = q3 - r7;
            acc0 += r0*lvt[0] + r1*lvt[1] + r2*lvt[2] + r3*lvt[3]
                  + r4*lvt[4] + r5*lvt[5] + r6*lvt[6] + r7*lvt[7];
        }
        {   // row s+16
            float f0 = (h & 2) ? g0b : 1.f - g0b;
            float f1 = (h & 1) ? g1b : 1.f - g1b;
            float pre = f0 * f1;
            float p1 = pre * g2b, p0 = pre - p1;
            float q1 = p0 * g3ab, q0 = p0 - q1;
            float q3 = p1 * g3bb, q2 = p1 - q3;
            float r1 = q0 * g4ab, r0 = q0 - r1;
            float r3 = q1 * g4bb, r2 = q1 - r3;
            float r5 = q2 * g4cb, r4 = q2 - r5;
            float r7 = q3 * g4db, r6 = q3 - r7;
            acc1 += r0*lvt[0] + r1*lvt[1] + r2*lvt[2] + r3*lvt[3]
                  + r4*lvt[4] + r5*lvt[5] + r6*lvt[6] + r7*lvt[7];
        }
    }

    // cross-quarter reduce inside the wave; out1 = 1 - out0 (prob mass sums to 1)
    acc0 += __shfl_xor(acc0, 16, 64);
    acc0 += __shfl_xor(acc0, 32, 64);
    acc1 += __shfl_xor(acc1, 16, 64);
    acc1 += __shfl_xor(acc1, 32, 64);
    if (h == 0) {
        float2 o0; o0.x = acc0; o0.y = 1.f - acc0;
        *(float2*)(out + (size_t)(rowBase + s) * 2) = o0;
        float2 o1; o1.x = acc1; o1.y = 1.f - acc1;
        *(float2*)(out + (size_t)(rowBase + 16 + s) * 2) = o1;
    }
}

extern "C" void kernel_launch(void* const* d_in, const int* in_sizes, int n_in,
                              void* d_out, int out_size, void* d_ws, size_t ws_size,
                              hipStream_t stream) {
    const float* x  = (const float*)d_in[0];
    const float* sw = (const float*)d_in[1];
    const float* sb = (const float*)d_in[2];
    const float* ll = (const float*)d_in[3];
    const float* tw = (const float*)d_in[4];
    const float* fm = (const float*)d_in[5];
    float* out = (float*)d_out;

    short* w_all  = (short*)d_ws;                         // 20*32*128*2 = 163840 B
    float* bias_p = (float*)((char*)d_ws + 163840);       // 2560 B
    float* lv0    = (float*)((char*)d_ws + 166400);       // 2560 B

    dim3 pgrid(T_TREES, 8);
    nrf_prep<<<pgrid, 256, 0, stream>>>(sw, sb, ll, tw, fm, w_all, bias_p, lv0);

    int B = in_sizes[0] / F_DIM;                          // 131072
    nrf_main<<<B / M_TILE, 256, 0, stream>>>(x, w_all, bias_p, lv0, out);
}

// Round 6
// 173.587 us; speedup vs baseline: 1.2080x; 1.0871x over previous
//
#include <hip/hip_runtime.h>

typedef __attribute__((ext_vector_type(8))) short bf16x8;
typedef __attribute__((ext_vector_type(4))) float floatx4;

#define T_TREES 20
#define N_NODES 32      // padded (31 real internal nodes)
#define F_DIM 128
#define M_TILE 128      // 4 waves x 32 rows, wave-private leaf phase
#define S_SP 36         // sp stride (dwords): 32 rows + 4 pad (reads <=2-way conflict)

#define NLOG2E 1.4426950408889634f   // sigmoid scale, applied in EPILOGUE (fma), not to weights

__device__ __forceinline__ short f2bf(float f) {
    unsigned u = __float_as_uint(f);
    u += 0x7fffu + ((u >> 16) & 1u);   // RNE — matches numpy/ml_dtypes bf16 cast
    return (short)(u >> 16);
}
__device__ __forceinline__ float bf2f(short h) {
    return __uint_as_float(((unsigned)(unsigned short)h) << 16);
}

// sigma(z) with u = -z*log2(e) already: 1/(1+2^u). 2 VALU + 2 trans ops.
__device__ __forceinline__ float sig_from_scaled(float u) {
    return __builtin_amdgcn_rcpf(1.f + __builtin_amdgcn_exp2f(u));
}

// ---------------- prep: RAW bf16 masked weights (unscaled -> exact bf16 grid).
// Parallel: grid (20 trees, 8 node-slices); tw staged via LDS; softmax order identical.
__global__ void nrf_prep(const float* __restrict__ sw, const float* __restrict__ sb,
                         const float* __restrict__ ll, const float* __restrict__ tw,
                         const float* __restrict__ fm,
                         short* __restrict__ w_all, float* __restrict__ bias_p,
                         float* __restrict__ lv0) {
    int t = blockIdx.x, slice = blockIdx.y, tid = threadIdx.x;

    const float* fmt = fm + t * F_DIM;
    const float* swt = sw + t * 31 * F_DIM;
    int idx = slice * 512 + tid;          // 4 nodes x 128 feats per slice
    #pragma unroll
    for (int r = 0; r < 2; ++r, idx += 256) {
        int n = idx >> 7, f = idx & 127;
        // mask is 0/1: bf16(sw*fm) == bf16(sw)*fm exactly. Store UNSCALED bf16.
        short wb = (n < 31 && fmt[f] != 0.f) ? f2bf(swt[n * F_DIM + f]) : (short)0;
        w_all[t * (N_NODES * F_DIM) + idx] = wb;
    }

    if (slice == 0) {
        __shared__ float tws[T_TREES];
        if (tid < T_TREES) tws[tid] = tw[tid];
        __syncthreads();
        if (tid < N_NODES) {
            // same reduction ORDER as the verified kernel -> bit-identical wt
            float m = -1e30f;
            for (int i = 0; i < T_TREES; ++i) m = fmaxf(m, bf2f(f2bf(tws[i])));
            float s = 0.f;
            for (int i = 0; i < T_TREES; ++i) s += __expf(bf2f(f2bf(tws[i])) - m);
            float wt = __expf(bf2f(f2bf(tws[t])) - m) / s;

            float bv = (tid < 31) ? bf2f(f2bf(sb[t * 31 + tid])) : 0.f;
            bias_p[t * N_NODES + tid] = bv * (-NLOG2E);
            float a  = bf2f(f2bf(ll[(t * 32 + tid) * 2 + 0]));
            float bb = bf2f(f2bf(ll[(t * 32 + tid) * 2 + 1]));
            float mx = fmaxf(a, bb);
            float e0 = __expf(a - mx), e1 = __expf(bb - mx);
            lv0[t * N_NODES + tid] = wt * e0 / (e0 + e1);
        }
    }
}

// ---------------- main: r2-verified per-tree math; NEW: explicit ping-pong B-prefetch
// (issue tree t+1's 8 loads before tree t's compute) + launch_bounds(256,4) so the
// compiler's VGPR budget (128) can hold the 2-deep pipeline. Occupancy is grid-capped
// at 4 waves/SIMD anyway, so the wider register budget is free.
__global__ __launch_bounds__(256, 4) void nrf_main(const float* __restrict__ x,
        const short* __restrict__ w_all, const float* __restrict__ bias_p,
        const float* __restrict__ lv0, float* __restrict__ out) {
    __shared__ float sp_all[4][N_NODES * S_SP];   // one patch per wave
    __shared__ float lv_s[T_TREES * N_NODES];
    __shared__ float bias_s[T_TREES * N_NODES];

    int tid = threadIdx.x;
    int wave = tid >> 6, lane = tid & 63;
    int q = lane >> 4, c16 = lane & 15;

    for (int i = tid; i < T_TREES * N_NODES; i += 256) { lv_s[i] = lv0[i]; bias_s[i] = bias_p[i]; }

    float* spb = sp_all[wave];
    int rowBase = blockIdx.x * M_TILE + wave * 32;   // this wave's 32 rows

    // A fragments: bf16(x), reused by all 20 trees -> registers. A-layout m=lane&15, k=q*8+j.
    bf16x8 afrag[2][4];
    #pragma unroll
    for (int mi = 0; mi < 2; ++mi) {
        const float* xr = x + (size_t)(rowBase + mi * 16 + c16) * F_DIM;
        #pragma unroll
        for (int ks = 0; ks < 4; ++ks) {
            const float4* p = (const float4*)(xr + ks * 32 + q * 8);
            float4 f0 = p[0], f1 = p[1];
            bf16x8 v;
            v[0]=f2bf(f0.x); v[1]=f2bf(f0.y); v[2]=f2bf(f0.z); v[3]=f2bf(f0.w);
            v[4]=f2bf(f1.x); v[5]=f2bf(f1.y); v[6]=f2bf(f1.z); v[7]=f2bf(f1.w);
            afrag[mi][ks] = v;
        }
    }

    int s = lane & 15, h = lane >> 4;   // leaf job: rows s & s+16, quarter-subtree h
    int s_node = 3 + h;                 // quarter root (level-2 node)
    float acc0 = 0.f, acc1 = 0.f;

    // prefetch tree 0 into buffer 0 (ping-pong; full unroll makes parity static)
    bf16x8 bpp[2][2][4];
    {
        const short* wtp = w_all;
        #pragma unroll
        for (int ni = 0; ni < 2; ++ni) {
            const short* wr = wtp + (ni * 16 + c16) * F_DIM;
            #pragma unroll
            for (int ks = 0; ks < 4; ++ks)
                bpp[0][ni][ks] = *(const bf16x8*)(wr + ks * 32 + q * 8);
        }
    }

    __syncthreads();                    // ONLY barrier: lv_s/bias_s ready

    #pragma unroll
    for (int t = 0; t < T_TREES; ++t) {
        const int cur = t & 1, nxt = cur ^ 1;   // static under full unroll
        // issue NEXT tree's loads first: their ~L2/L3 latency hides under this
        // tree's MFMA + epilogue + leaf phase (~600-800 cyc of work).
        if (t + 1 < T_TREES) {
            const short* wtp = w_all + (t + 1) * (N_NODES * F_DIM);
            #pragma unroll
            for (int ni = 0; ni < 2; ++ni) {
                const short* wr = wtp + (ni * 16 + c16) * F_DIM;
                #pragma unroll
                for (int ks = 0; ks < 4; ++ks)
                    bpp[nxt][ni][ks] = *(const bf16x8*)(wr + ks * 32 + q * 8);
            }
        }

        floatx4 acc[2][2];
        #pragma unroll
        for (int mi = 0; mi < 2; ++mi)
            #pragma unroll
            for (int ni = 0; ni < 2; ++ni)
                acc[mi][ni] = (floatx4){0.f,0.f,0.f,0.f};
        #pragma unroll
        for (int ks = 0; ks < 4; ++ks)
            #pragma unroll
            for (int mi = 0; mi < 2; ++mi)
                #pragma unroll
                for (int ni = 0; ni < 2; ++ni)
                    acc[mi][ni] = __builtin_amdgcn_mfma_f32_16x16x32_bf16(
                        afrag[mi][ks], bpp[cur][ni][ks], acc[mi][ni], 0, 0, 0);

        // epilogue: u = fma(acc, -log2e, bias*(-log2e)); sigma = rcp(1+exp2(u));
        // transposed wave-private store
        #pragma unroll
        for (int ni = 0; ni < 2; ++ni) {
            int col = ni * 16 + c16;
            float bv = bias_s[t * N_NODES + col];
            #pragma unroll
            for (int mi = 0; mi < 2; ++mi) {
                float4 v;
                v.x = sig_from_scaled(fmaf(acc[mi][ni][0], -NLOG2E, bv));
                v.y = sig_from_scaled(fmaf(acc[mi][ni][1], -NLOG2E, bv));
                v.z = sig_from_scaled(fmaf(acc[mi][ni][2], -NLOG2E, bv));
                v.w = sig_from_scaled(fmaf(acc[mi][ni][3], -NLOG2E, bv));
                *(float4*)&spb[col * S_SP + mi * 16 + q * 4] = v;
            }
        }
        // leaf phase: wave-private LDS, DS ops in-order per wave -> NO barrier.
        float g0a = spb[s],                          g0b = spb[s + 16];
        int n1 = 1 + (h >> 1);
        float g1a = spb[n1 * S_SP + s],              g1b = spb[n1 * S_SP + s + 16];
        float g2a = spb[s_node * S_SP + s],          g2b = spb[s_node * S_SP + s + 16];
        int n3a = 2 * s_node + 1, n3b = 2 * s_node + 2;
        float g3aa = spb[n3a * S_SP + s],            g3ab = spb[n3a * S_SP + s + 16];
        float g3ba = spb[n3b * S_SP + s],            g3bb = spb[n3b * S_SP + s + 16];
        int n4 = 4 * s_node + 3;
        float g4aa = spb[n4 * S_SP + s],             g4ab = spb[n4 * S_SP + s + 16];
        float g4ba = spb[(n4+1) * S_SP + s],         g4bb = spb[(n4+1) * S_SP + s + 16];
        float g4ca = spb[(n4+2) * S_SP + s],         g4cb = spb[(n4+2) * S_SP + s + 16];
        float g4da = spb[(n4+3) * S_SP + s],         g4db = spb[(n4+3) * S_SP + s + 16];

        const float* lvt = &lv_s[t * N_NODES + h * 8];  // shared by both rows

        {   // row s
            float f0 = (h & 2) ? g0a : 1.f - g0a;
            float f1 = (h & 1) ? g1a : 1.f - g1a;
            float pre = f0 * f1;
            float p1 = pre * g2a, p0 = pre - p1;
            float q1 = p0 * g3aa, q0 = p0 - q1;
            float q3 = p1 * g3ba, q2 = p1 - q3;
            float r1 = q0 * g4aa, r0 = q0 - r1;
            float r3 = q1 * g4ba, r2 = q1 - r3;
            float r5 = q2 * g4ca, r4 = q2 - r5;
            float r7 = q3 * g4da, r6 = q3 - r7;
            acc0 += r0*lvt[0] + r1*lvt[1] + r2*lvt[2] + r3*lvt[3]
                  + r4*lvt[4] + r5*lvt[5] + r6*lvt[6] + r7*lvt[7];
        }
        {   // row s+16
            float f0 = (h & 2) ? g0b : 1.f - g0b;
            float f1 = (h & 1) ? g1b : 1.f - g1b;
            float pre = f0 * f1;
            float p1 = pre * g2b, p0 = pre - p1;
            float q1 = p0 * g3ab, q0 = p0 - q1;
            float q3 = p1 * g3bb, q2 = p1 - q3;
            float r1 = q0 * g4ab, r0 = q0 - r1;
            float r3 = q1 * g4bb, r2 = q1 - r3;
            float r5 = q2 * g4cb, r4 = q2 - r5;
            float r7 = q3 * g4db, r6 = q3 - r7;
            acc1 += r0*lvt[0] + r1*lvt[1] + r2*lvt[2] + r3*lvt[3]
                  + r4*lvt[4] + r5*lvt[5] + r6*lvt[6] + r7*lvt[7];
        }
    }

    // cross-quarter reduce inside the wave; out1 = 1 - out0 (prob mass sums to 1)
    acc0 += __shfl_xor(acc0, 16, 64);
    acc0 += __shfl_xor(acc0, 32, 64);
    acc1 += __shfl_xor(acc1, 16, 64);
    acc1 += __shfl_xor(acc1, 32, 64);
    if (h == 0) {
        float2 o0; o0.x = acc0; o0.y = 1.f - acc0;
        *(float2*)(out + (size_t)(rowBase + s) * 2) = o0;
        float2 o1; o1.x = acc1; o1.y = 1.f - acc1;
        *(float2*)(out + (size_t)(rowBase + 16 + s) * 2) = o1;
    }
}

extern "C" void kernel_launch(void* const* d_in, const int* in_sizes, int n_in,
                              void* d_out, int out_size, void* d_ws, size_t ws_size,
                              hipStream_t stream) {
    const float* x  = (const float*)d_in[0];
    const float* sw = (const float*)d_in[1];
    const float* sb = (const float*)d_in[2];
    const float* ll = (const float*)d_in[3];
    const float* tw = (const float*)d_in[4];
    const float* fm = (const float*)d_in[5];
    float* out = (float*)d_out;

    short* w_all  = (short*)d_ws;                         // 20*32*128*2 = 163840 B
    float* bias_p = (float*)((char*)d_ws + 163840);       // 2560 B
    float* lv0    = (float*)((char*)d_ws + 166400);       // 2560 B

    dim3 pgrid(T_TREES, 8);
    nrf_prep<<<pgrid, 256, 0, stream>>>(sw, sb, ll, tw, fm, w_all, bias_p, lv0);

    int B = in_sizes[0] / F_DIM;                          // 131072
    nrf_main<<<B / M_TILE, 256, 0, stream>>>(x, w_all, bias_p, lv0, out);
}

// Round 8
// 139.987 us; speedup vs baseline: 1.4979x; 1.2400x over previous
//
#include <hip/hip_runtime.h>

typedef __attribute__((ext_vector_type(8))) short bf16x8;
typedef __attribute__((ext_vector_type(4))) float floatx4;

#define T_TREES 20
#define N_NODES 32      // padded (31 real internal nodes)
#define F_DIM 128
#define M_TILE 128      // 4 waves x 32 rows, wave-private leaf phase
#define S_SP 36         // sp stride (dwords): 32 rows + 4 pad (reads <=2-way conflict)

#define NLOG2E 1.4426950408889634f   // sigmoid scale, applied in EPILOGUE (fma), not to weights

__device__ __forceinline__ short f2bf(float f) {
    unsigned u = __float_as_uint(f);
    u += 0x7fffu + ((u >> 16) & 1u);   // RNE — matches numpy/ml_dtypes bf16 cast
    return (short)(u >> 16);
}
__device__ __forceinline__ float bf2f(short h) {
    return __uint_as_float(((unsigned)(unsigned short)h) << 16);
}

// sigma(z) with u = -z*log2(e) already: 1/(1+2^u). 2 VALU + 2 trans ops.
__device__ __forceinline__ float sig_from_scaled(float u) {
    return __builtin_amdgcn_rcpf(1.f + __builtin_amdgcn_exp2f(u));
}

// ---------------- prep: RAW bf16 masked weights (unscaled -> exact bf16 grid).
// Parallel: grid (20 trees, 8 node-slices); tw staged via LDS; softmax order identical.
__global__ void nrf_prep(const float* __restrict__ sw, const float* __restrict__ sb,
                         const float* __restrict__ ll, const float* __restrict__ tw,
                         const float* __restrict__ fm,
                         short* __restrict__ w_all, float* __restrict__ bias_p,
                         float* __restrict__ lv0) {
    int t = blockIdx.x, slice = blockIdx.y, tid = threadIdx.x;

    const float* fmt = fm + t * F_DIM;
    const float* swt = sw + t * 31 * F_DIM;
    int idx = slice * 512 + tid;          // 4 nodes x 128 feats per slice
    #pragma unroll
    for (int r = 0; r < 2; ++r, idx += 256) {
        int n = idx >> 7, f = idx & 127;
        // mask is 0/1: bf16(sw*fm) == bf16(sw)*fm exactly. Store UNSCALED bf16.
        short wb = (n < 31 && fmt[f] != 0.f) ? f2bf(swt[n * F_DIM + f]) : (short)0;
        w_all[t * (N_NODES * F_DIM) + idx] = wb;
    }

    if (slice == 0) {
        __shared__ float tws[T_TREES];
        if (tid < T_TREES) tws[tid] = tw[tid];
        __syncthreads();
        if (tid < N_NODES) {
            // same reduction ORDER as the verified kernel -> bit-identical wt
            float m = -1e30f;
            for (int i = 0; i < T_TREES; ++i) m = fmaxf(m, bf2f(f2bf(tws[i])));
            float s = 0.f;
            for (int i = 0; i < T_TREES; ++i) s += __expf(bf2f(f2bf(tws[i])) - m);
            float wt = __expf(bf2f(f2bf(tws[t])) - m) / s;

            float bv = (tid < 31) ? bf2f(f2bf(sb[t * 31 + tid])) : 0.f;
            bias_p[t * N_NODES + tid] = bv * (-NLOG2E);
            float a  = bf2f(f2bf(ll[(t * 32 + tid) * 2 + 0]));
            float bb = bf2f(f2bf(ll[(t * 32 + tid) * 2 + 1]));
            float mx = fmaxf(a, bb);
            float e0 = __expf(a - mx), e1 = __expf(bb - mx);
            lv0[t * N_NODES + tid] = wt * e0 / (e0 + e1);
        }
    }
}

// ---------------- main: r2-verified per-tree math; NEW: per-BLOCK cooperative LDS
// staging of each tree's 8 KB weights (double-buffered, 1 barrier/tree). Cuts w_all
// L2 traffic 4x (each wave previously re-read all 160 KB privately: 655 MB/dispatch,
// ~80% of aggregate L2 BW -> the measured stall). B bytes identical -> bit-identical out.
__global__ __launch_bounds__(256, 4) void nrf_main(const float* __restrict__ x,
        const short* __restrict__ w_all, const float* __restrict__ bias_p,
        const float* __restrict__ lv0, float* __restrict__ out) {
    __shared__ short bstage[2][N_NODES * F_DIM];  // 2 x 8 KB, XOR-swizzled rows
    __shared__ float sp_all[4][N_NODES * S_SP];   // one patch per wave
    __shared__ float lv_s[T_TREES * N_NODES];
    __shared__ float bias_s[T_TREES * N_NODES];

    int tid = threadIdx.x;
    int wave = tid >> 6, lane = tid & 63;
    int q = lane >> 4, c16 = lane & 15;

    for (int i = tid; i < T_TREES * N_NODES; i += 256) { lv_s[i] = lv0[i]; bias_s[i] = bias_p[i]; }

    float* spb = sp_all[wave];
    int rowBase = blockIdx.x * M_TILE + wave * 32;   // this wave's 32 rows

    // A fragments: bf16(x), reused by all 20 trees -> registers. A-layout m=lane&15, k=q*8+j.
    bf16x8 afrag[2][4];
    #pragma unroll
    for (int mi = 0; mi < 2; ++mi) {
        const float* xr = x + (size_t)(rowBase + mi * 16 + c16) * F_DIM;
        #pragma unroll
        for (int ks = 0; ks < 4; ++ks) {
            const float4* p = (const float4*)(xr + ks * 32 + q * 8);
            float4 f0 = p[0], f1 = p[1];
            bf16x8 v;
            v[0]=f2bf(f0.x); v[1]=f2bf(f0.y); v[2]=f2bf(f0.z); v[3]=f2bf(f0.w);
            v[4]=f2bf(f1.x); v[5]=f2bf(f1.y); v[6]=f2bf(f1.z); v[7]=f2bf(f1.w);
            afrag[mi][ks] = v;
        }
    }

    // staging geometry: thread tid owns bytes [tid*32, tid*32+32) of the 8 KB tree
    // image (row n = tid>>3). Swizzle: phys = lin ^ ((row&7)<<4), same fn on read.
    const unsigned soff0 = (unsigned)(tid * 32) ^ ((unsigned)((tid >> 3) & 7) << 4);
    const bf16x8* wsrc = (const bf16x8*)w_all + tid * 2;   // 2 x 16B chunks per thread

    // prologue: stage tree 0 into bstage[0]
    {
        bf16x8 s0 = wsrc[0], s1 = wsrc[1];
        *(bf16x8*)((char*)bstage[0] + soff0) = s0;
        *(bf16x8*)((char*)bstage[0] + (soff0 ^ 16u)) = s1;
    }

    int s = lane & 15, h = lane >> 4;   // leaf job: rows s & s+16, quarter-subtree h
    int s_node = 3 + h;                 // quarter root (level-2 node)
    float acc0 = 0.f, acc1 = 0.f;
    __syncthreads();                    // lv/bias + tree-0 stage ready

    #pragma unroll
    for (int t = 0; t < T_TREES; ++t) {
        const int cur = t & 1, nxt = cur ^ 1;   // static under full unroll
        // 1) issue next tree's global loads EARLY (latency hides under this tree)
        bf16x8 pf0, pf1;
        if (t + 1 < T_TREES) {
            const bf16x8* src = (const bf16x8*)(w_all + (t + 1) * (N_NODES * F_DIM)) + tid * 2;
            pf0 = src[0]; pf1 = src[1];
        }

        // 2) B fragments from LDS (swizzled read, bytes identical to global path)
        bf16x8 bfrag[2][4];
        const char* bb = (const char*)bstage[cur];
        #pragma unroll
        for (int ni = 0; ni < 2; ++ni) {
            unsigned row = (unsigned)(ni * 16 + c16);
            unsigned swz = (row & 7u) << 4;
            #pragma unroll
            for (int ks = 0; ks < 4; ++ks) {
                unsigned lin = row * 256u + (unsigned)(ks * 64 + q * 16);
                bfrag[ni][ks] = *(const bf16x8*)(bb + (lin ^ swz));
            }
        }

        floatx4 acc[2][2];
        #pragma unroll
        for (int mi = 0; mi < 2; ++mi)
            #pragma unroll
            for (int ni = 0; ni < 2; ++ni)
                acc[mi][ni] = (floatx4){0.f,0.f,0.f,0.f};
        #pragma unroll
        for (int ks = 0; ks < 4; ++ks)
            #pragma unroll
            for (int mi = 0; mi < 2; ++mi)
                #pragma unroll
                for (int ni = 0; ni < 2; ++ni)
                    acc[mi][ni] = __builtin_amdgcn_mfma_f32_16x16x32_bf16(
                        afrag[mi][ks], bfrag[ni][ks], acc[mi][ni], 0, 0, 0);

        // epilogue: u = fma(acc, -log2e, bias*(-log2e)); sigma = rcp(1+exp2(u));
        // transposed wave-private store
        #pragma unroll
        for (int ni = 0; ni < 2; ++ni) {
            int col = ni * 16 + c16;
            float bv = bias_s[t * N_NODES + col];
            #pragma unroll
            for (int mi = 0; mi < 2; ++mi) {
                float4 v;
                v.x = sig_from_scaled(fmaf(acc[mi][ni][0], -NLOG2E, bv));
                v.y = sig_from_scaled(fmaf(acc[mi][ni][1], -NLOG2E, bv));
                v.z = sig_from_scaled(fmaf(acc[mi][ni][2], -NLOG2E, bv));
                v.w = sig_from_scaled(fmaf(acc[mi][ni][3], -NLOG2E, bv));
                *(float4*)&spb[col * S_SP + mi * 16 + q * 4] = v;
            }
        }
        // leaf phase: wave-private LDS, DS ops in-order per wave -> no extra wait.
        float g0a = spb[s],                          g0b = spb[s + 16];
        int n1 = 1 + (h >> 1);
        float g1a = spb[n1 * S_SP + s],              g1b = spb[n1 * S_SP + s + 16];
        float g2a = spb[s_node * S_SP + s],          g2b = spb[s_node * S_SP + s + 16];
        int n3a = 2 * s_node + 1, n3b = 2 * s_node + 2;
        float g3aa = spb[n3a * S_SP + s],            g3ab = spb[n3a * S_SP + s + 16];
        float g3ba = spb[n3b * S_SP + s],            g3bb = spb[n3b * S_SP + s + 16];
        int n4 = 4 * s_node + 3;
        float g4aa = spb[n4 * S_SP + s],             g4ab = spb[n4 * S_SP + s + 16];
        float g4ba = spb[(n4+1) * S_SP + s],         g4bb = spb[(n4+1) * S_SP + s + 16];
        float g4ca = spb[(n4+2) * S_SP + s],         g4cb = spb[(n4+2) * S_SP + s + 16];
        float g4da = spb[(n4+3) * S_SP + s],         g4db = spb[(n4+3) * S_SP + s + 16];

        const float* lvt = &lv_s[t * N_NODES + h * 8];  // shared by both rows

        {   // row s
            float f0 = (h & 2) ? g0a : 1.f - g0a;
            float f1 = (h & 1) ? g1a : 1.f - g1a;
            float pre = f0 * f1;
            float p1 = pre * g2a, p0 = pre - p1;
            float q1 = p0 * g3aa, q0 = p0 - q1;
            float q3 = p1 * g3ba, q2 = p1 - q3;
            float r1 = q0 * g4aa, r0 = q0 - r1;
            float r3 = q1 * g4ba, r2 = q1 - r3;
            float r5 = q2 * g4ca, r4 = q2 - r5;
            float r7 = q3 * g4da, r6 = q3 - r7;
            acc0 += r0*lvt[0] + r1*lvt[1] + r2*lvt[2] + r3*lvt[3]
                  + r4*lvt[4] + r5*lvt[5] + r6*lvt[6] + r7*lvt[7];
        }
        {   // row s+16
            float f0 = (h & 2) ? g0b : 1.f - g0b;
            float f1 = (h & 1) ? g1b : 1.f - g1b;
            float pre = f0 * f1;
            float p1 = pre * g2b, p0 = pre - p1;
            float q1 = p0 * g3ab, q0 = p0 - q1;
            float q3 = p1 * g3bb, q2 = p1 - q3;
            float r1 = q0 * g4ab, r0 = q0 - r1;
            float r3 = q1 * g4bb, r2 = q1 - r3;
            float r5 = q2 * g4cb, r4 = q2 - r5;
            float r7 = q3 * g4db, r6 = q3 - r7;
            acc1 += r0*lvt[0] + r1*lvt[1] + r2*lvt[2] + r3*lvt[3]
                  + r4*lvt[4] + r5*lvt[5] + r6*lvt[6] + r7*lvt[7];
        }

        // 3) write the prefetched tree into the other buffer, then one barrier.
        if (t + 1 < T_TREES) {
            *(bf16x8*)((char*)bstage[nxt] + soff0) = pf0;
            *(bf16x8*)((char*)bstage[nxt] + (soff0 ^ 16u)) = pf1;
        }
        __syncthreads();
    }

    // cross-quarter reduce inside the wave; out1 = 1 - out0 (prob mass sums to 1)
    acc0 += __shfl_xor(acc0, 16, 64);
    acc0 += __shfl_xor(acc0, 32, 64);
    acc1 += __shfl_xor(acc1, 16, 64);
    acc1 += __shfl_xor(acc1, 32, 64);
    if (h == 0) {
        float2 o0; o0.x = acc0; o0.y = 1.f - acc0;
        *(float2*)(out + (size_t)(rowBase + s) * 2) = o0;
        float2 o1; o1.x = acc1; o1.y = 1.f - acc1;
        *(float2*)(out + (size_t)(rowBase + 16 + s) * 2) = o1;
    }
}

extern "C" void kernel_launch(void* const* d_in, const int* in_sizes, int n_in,
                              void* d_out, int out_size, void* d_ws, size_t ws_size,
                              hipStream_t stream) {
    const float* x  = (const float*)d_in[0];
    const float* sw = (const float*)d_in[1];
    const float* sb = (const float*)d_in[2];
    const float* ll = (const float*)d_in[3];
    const float* tw = (const float*)d_in[4];
    const float* fm = (const float*)d_in[5];
    float* out = (float*)d_out;

    short* w_all  = (short*)d_ws;                         // 20*32*128*2 = 163840 B
    float* bias_p = (float*)((char*)d_ws + 163840);       // 2560 B
    float* lv0    = (float*)((char*)d_ws + 166400);       // 2560 B

    dim3 pgrid(T_TREES, 8);
    nrf_prep<<<pgrid, 256, 0, stream>>>(sw, sb, ll, tw, fm, w_all, bias_p, lv0);

    int B = in_sizes[0] / F_DIM;                          // 131072
    nrf_main<<<B / M_TILE, 256, 0, stream>>>(x, w_all, bias_p, lv0, out);
}